// Round 7
// baseline (17192.374 us; speedup 1.0000x reference)
//
#include <hip/hip_runtime.h>
#include <hip/hip_bf16.h>

// GNNRecommender: LSTM(20) + content linear + 2x bipartite SAGE (CSR gather) + classifier.
// Round 7: probe v3 (bit-pattern fragments through memory, no bf16 casts/inserts),
// split LSTM kernels (MFMA w/ measured LUT || register-gate VALU w/ transposed
// weights), timing side-channel diag kernel.

typedef __bf16 bf16;
typedef __bf16 bf16x2 __attribute__((ext_vector_type(2)));
typedef __bf16 bf16x8 __attribute__((ext_vector_type(8)));
typedef short short4v __attribute__((ext_vector_type(4)));
typedef float floatx4 __attribute__((ext_vector_type(4)));

#if __has_builtin(__builtin_amdgcn_mfma_f32_16x16x16bf16_1k)
#define HAVE16 1
#else
#define HAVE16 0
#endif

#define N_NODES 32768
#define NMASK 32767
#define T_STEPS 20
#define EMBD 64
#define HD 128
#define G4 512   // 4*H gate width
#define KTOT 192 // 64 (x) + 128 (h)

__device__ __forceinline__ float sigf(float x) { return 1.f / (1.f + __expf(-x)); }

__device__ __forceinline__ float ldf(const void* p, size_t i, int isbf) {
  return isbf ? (float)((const bf16*)p)[i] : ((const float*)p)[i];
}

// exact-integer probe matrices (small ints => exact in bf16 and fp32)
__device__ __forceinline__ float A3f(int m, int k) { return (float)((m * 37 + k * 11) % 13 - 6); }
__device__ __forceinline__ float B3f(int k, int n) { return (float)((k * 7 + n * 29) % 11 - 5); }
// bf16 bit pattern of an exact small float (pure integer ops)
__device__ __forceinline__ unsigned short bfb(float f) {
  return (unsigned short)(__float_as_uint(f) >> 16);
}

// ---------------- dtype probe: flag=1 bf16, 0 fp32 ----------------
__global__ void k_detect(const unsigned* __restrict__ x, int* __restrict__ flag)
{
  if (threadIdx.x == 0 && blockIdx.x == 0) {
    int cnt = 0;
    for (int i = 0; i < 256; ++i) {
      const unsigned w = x[i];
      const unsigned e0 = (w >> 7) & 0xffu;
      const unsigned e1 = (w >> 23) & 0xffu;
      const bool ok0 = (e0 >= 90u && e0 <= 141u) || ((w & 0x7fffu) == 0u);
      const bool ok1 = (e1 >= 90u && e1 <= 141u) || (((w >> 16) & 0x7fffu) == 0u);
      if (ok0 && ok1) ++cnt;
    }
    *flag = (cnt >= 200) ? 1 : 0;
  }
}

__global__ __launch_bounds__(256) void k_zero_int(int* __restrict__ p, int n)
{
  const int i = blockIdx.x * 256 + threadIdx.x;
  if (i < n) p[i] = 0;
}

// ================= MFMA probe v3 =================
// Fragments constructed as uint16 bit patterns, stored to global scratch, loaded
// back as vectors (mirrors real-kernel load path; zero bf16 casts/inserts).
// Label-LUT decode works for ANY bijective C/D layout and any A/B role swap;
// exact-integer r3 product check catches k-map twists / broken lowering.
__global__ __launch_bounds__(64) void k_probe(
    unsigned short* __restrict__ fr,
    int* __restrict__ lut32, int* __restrict__ ok32p,
    int* __restrict__ lut16, int* __restrict__ ok16p)
{
  __shared__ int seen[256];
  __shared__ int fail;
  const int lane = threadIdx.x;
  const int mrow = lane & 15, quad = lane >> 4;
  const floatx4 vz = {0.f, 0.f, 0.f, 0.f};

  // ---------- variant 1: v_mfma_f32_16x16x32_bf16 ----------
  unsigned short* fa1 = fr + 0 * 512;   // [64][8] each
  unsigned short* fb1 = fr + 1 * 512;
  unsigned short* fa2 = fr + 2 * 512;
  unsigned short* fb2 = fr + 3 * 512;
  unsigned short* fa3 = fr + 4 * 512;
  unsigned short* fb3 = fr + 5 * 512;
  for (int j = 0; j < 8; ++j) {
    fa1[lane * 8 + j] = bfb((float)(mrow + 1));
    fb1[lane * 8 + j] = bfb(1.0f);
    fa2[lane * 8 + j] = bfb(1.0f);
    fb2[lane * 8 + j] = bfb((float)(mrow + 1));
    fa3[lane * 8 + j] = bfb(A3f(mrow, quad * 8 + j));
    fb3[lane * 8 + j] = bfb(B3f(quad * 8 + j, mrow));
  }
  for (int i = lane; i < 256; i += 64) seen[i] = 0;
  if (lane == 0) fail = 0;
  __syncthreads();
  {
    bf16x8 a1 = *(const bf16x8*)(fa1 + lane * 8);
    bf16x8 b1 = *(const bf16x8*)(fb1 + lane * 8);
    bf16x8 a2 = *(const bf16x8*)(fa2 + lane * 8);
    bf16x8 b2 = *(const bf16x8*)(fb2 + lane * 8);
    bf16x8 a3 = *(const bf16x8*)(fa3 + lane * 8);
    bf16x8 b3 = *(const bf16x8*)(fb3 + lane * 8);
    floatx4 r1 = __builtin_amdgcn_mfma_f32_16x16x32_bf16(a1, b1, vz, 0, 0, 0);
    floatx4 r2 = __builtin_amdgcn_mfma_f32_16x16x32_bf16(a2, b2, vz, 0, 0, 0);
    floatx4 r3 = __builtin_amdgcn_mfma_f32_16x16x32_bf16(a3, b3, vz, 0, 0, 0);
    #pragma unroll
    for (int reg = 0; reg < 4; ++reg) {
      const int m = __float2int_rn(r1[reg] * (1.f / 32.f)) - 1;
      const int n = __float2int_rn(r2[reg] * (1.f / 32.f)) - 1;
      bool good = (m >= 0 && m < 16 && n >= 0 && n < 16)
               && fabsf(r1[reg] - 32.f * (m + 1)) < 0.5f
               && fabsf(r2[reg] - 32.f * (n + 1)) < 0.5f;
      if (good) {
        float c3 = 0.f;
        for (int k = 0; k < 32; ++k) c3 += A3f(m, k) * B3f(k, n);
        good = fabsf(r3[reg] - c3) < 0.5f;
      }
      if (good) {
        atomicAdd(&seen[m * 16 + n], 1);
        lut32[lane * 4 + reg] = (m << 4) | n;
      } else fail = 1;
    }
  }
  __syncthreads();
  {
    int bij = 1;
    for (int i = lane; i < 256; i += 64) if (seen[i] != 1) bij = 0;
    if (!bij) fail = 1;
  }
  __syncthreads();
  if (lane == 0) *ok32p = fail ? 0 : 1;
  __syncthreads();

  // ---------- variant 2: 16x16x16 bf16 (_1k builtin, short4 operands) ----------
  for (int i = lane; i < 256; i += 64) seen[i] = 0;
  if (lane == 0) fail = 0;
  __syncthreads();
#if HAVE16
  {
    unsigned short* ga1 = fr + 3072 + 0 * 256;   // [64][4] each
    unsigned short* gb1 = fr + 3072 + 1 * 256;
    unsigned short* ga2 = fr + 3072 + 2 * 256;
    unsigned short* gb2 = fr + 3072 + 3 * 256;
    unsigned short* ga3 = fr + 3072 + 4 * 256;
    unsigned short* gb3 = fr + 3072 + 5 * 256;
    for (int j = 0; j < 4; ++j) {
      ga1[lane * 4 + j] = bfb((float)(mrow + 1));
      gb1[lane * 4 + j] = bfb(1.0f);
      ga2[lane * 4 + j] = bfb(1.0f);
      gb2[lane * 4 + j] = bfb((float)(mrow + 1));
      ga3[lane * 4 + j] = bfb(A3f(mrow, quad * 4 + j));
      gb3[lane * 4 + j] = bfb(B3f(quad * 4 + j, mrow));
    }
    __syncthreads();
    short4v a1 = *(const short4v*)(ga1 + lane * 4);
    short4v b1 = *(const short4v*)(gb1 + lane * 4);
    short4v a2 = *(const short4v*)(ga2 + lane * 4);
    short4v b2 = *(const short4v*)(gb2 + lane * 4);
    short4v a3 = *(const short4v*)(ga3 + lane * 4);
    short4v b3 = *(const short4v*)(gb3 + lane * 4);
    floatx4 r1 = __builtin_amdgcn_mfma_f32_16x16x16bf16_1k(a1, b1, vz, 0, 0, 0);
    floatx4 r2 = __builtin_amdgcn_mfma_f32_16x16x16bf16_1k(a2, b2, vz, 0, 0, 0);
    floatx4 r3 = __builtin_amdgcn_mfma_f32_16x16x16bf16_1k(a3, b3, vz, 0, 0, 0);
    #pragma unroll
    for (int reg = 0; reg < 4; ++reg) {
      const int m = __float2int_rn(r1[reg] * (1.f / 16.f)) - 1;
      const int n = __float2int_rn(r2[reg] * (1.f / 16.f)) - 1;
      bool good = (m >= 0 && m < 16 && n >= 0 && n < 16)
               && fabsf(r1[reg] - 16.f * (m + 1)) < 0.5f
               && fabsf(r2[reg] - 16.f * (n + 1)) < 0.5f;
      if (good) {
        float c3 = 0.f;
        for (int k = 0; k < 16; ++k) c3 += A3f(m, k) * B3f(k, n);
        good = fabsf(r3[reg] - c3) < 0.5f;
      }
      if (good) {
        atomicAdd(&seen[m * 16 + n], 1);
        lut16[lane * 4 + reg] = (m << 4) | n;
      } else fail = 1;
    }
  }
  __syncthreads();
  {
    int bij = 1;
    for (int i = lane; i < 256; i += 64) if (seen[i] != 1) bij = 0;
    if (!bij) fail = 1;
  }
  __syncthreads();
  if (lane == 0) *ok16p = fail ? 0 : 1;
#else
  if (lane == 0) *ok16p = 0;
#endif
}

// ---------------- weight transpose: WT[k][row], k<64 from W_ih, else W_hh ----------
__global__ __launch_bounds__(256) void k_wt(const void* __restrict__ W_ih,
                                            const void* __restrict__ W_hh,
                                            bf16* __restrict__ WT,
                                            const int* __restrict__ flagp)
{
  const int isbf = *flagp;
  const int e = blockIdx.x * 256 + threadIdx.x;
  if (e >= KTOT * G4) return;
  const int k = e >> 9, row = e & 511;
  const float v = (k < EMBD) ? ldf(W_ih, (size_t)row * EMBD + k, isbf)
                             : ldf(W_hh, (size_t)row * HD + (k - EMBD), isbf);
  WT[e] = (bf16)v;
}

// ================= LSTM step: MFMA path (runs only if a probe verified) =========
__global__ __launch_bounds__(256) void k_lstm_mfma(
    const void* __restrict__ x_user, const void* __restrict__ W_ih,
    const void* __restrict__ W_hh, const void* __restrict__ b_ih,
    const void* __restrict__ b_hh,
    bf16* __restrict__ h_bf, float* __restrict__ cstate,
    const int* __restrict__ flagp, const int* __restrict__ ok32p,
    const int* __restrict__ ok16p, const int* __restrict__ lut32,
    const int* __restrict__ lut16, int t)
{
  const int isbf = *flagp;
  const int use32 = isbf && *ok32p;
  const int use16 = isbf && !use32 && *ok16p;
  if (!use32 && !use16) return;

  __shared__ float gates[32 * G4];          // 64 KB
  const int tid = threadIdx.x;
  const int n0 = blockIdx.x * 32;
  const bf16* xu = (const bf16*)x_user;
  const bf16* Wi = (const bf16*)W_ih;
  const bf16* Wh = (const bf16*)W_hh;
  const int wave = tid >> 6, lane = tid & 63;
  const int mrow = lane & 15, quad = lane >> 4;
  const int colbase = wave * 128;
  const floatx4 vz = {0.f, 0.f, 0.f, 0.f};
  floatx4 acc[2][8];
  #pragma unroll
  for (int r = 0; r < 2; ++r)
    #pragma unroll
    for (int c = 0; c < 8; ++c) acc[r][c] = vz;

  if (use32) {
    #pragma unroll
    for (int kc = 0; kc < 2; ++kc) {               // x_t @ W_ih^T (K=64)
      const int koff = kc * 32 + quad * 8;
      bf16x8 a[2];
      #pragma unroll
      for (int r = 0; r < 2; ++r)
        a[r] = *(const bf16x8*)(xu +
                 (size_t)(n0 + r * 16 + mrow) * (T_STEPS * EMBD) + (size_t)t * EMBD + koff);
      #pragma unroll
      for (int ct = 0; ct < 8; ++ct) {
        const int g = colbase + ct * 16 + mrow;
        bf16x8 b = *(const bf16x8*)(Wi + (size_t)g * EMBD + koff);
        #pragma unroll
        for (int r = 0; r < 2; ++r)
          acc[r][ct] = __builtin_amdgcn_mfma_f32_16x16x32_bf16(a[r], b, acc[r][ct], 0, 0, 0);
      }
    }
    if (t > 0) {                                   // h @ W_hh^T (K=128)
      #pragma unroll
      for (int kc = 0; kc < 4; ++kc) {
        const int koff = kc * 32 + quad * 8;
        bf16x8 a[2];
        #pragma unroll
        for (int r = 0; r < 2; ++r)
          a[r] = *(const bf16x8*)(h_bf + (size_t)(n0 + r * 16 + mrow) * HD + koff);
        #pragma unroll
        for (int ct = 0; ct < 8; ++ct) {
          const int g = colbase + ct * 16 + mrow;
          bf16x8 b = *(const bf16x8*)(Wh + (size_t)g * HD + koff);
          #pragma unroll
          for (int r = 0; r < 2; ++r)
            acc[r][ct] = __builtin_amdgcn_mfma_f32_16x16x32_bf16(a[r], b, acc[r][ct], 0, 0, 0);
        }
      }
    }
    int lm[4], ln[4];
    #pragma unroll
    for (int reg = 0; reg < 4; ++reg) {
      const int v = lut32[lane * 4 + reg];
      lm[reg] = v >> 4; ln[reg] = v & 15;
    }
    #pragma unroll
    for (int r = 0; r < 2; ++r)
      #pragma unroll
      for (int ct = 0; ct < 8; ++ct)
        #pragma unroll
        for (int reg = 0; reg < 4; ++reg)
          gates[(r * 16 + lm[reg]) * G4 + colbase + ct * 16 + ln[reg]] = acc[r][ct][reg];
  }
#if HAVE16
  else {
    #pragma unroll
    for (int kc = 0; kc < 4; ++kc) {               // x_t @ W_ih^T, K=64 in 4 chunks
      const int koff = kc * 16 + quad * 4;
      short4v a[2];
      #pragma unroll
      for (int r = 0; r < 2; ++r)
        a[r] = *(const short4v*)(xu +
                 (size_t)(n0 + r * 16 + mrow) * (T_STEPS * EMBD) + (size_t)t * EMBD + koff);
      #pragma unroll
      for (int ct = 0; ct < 8; ++ct) {
        const int g = colbase + ct * 16 + mrow;
        short4v b = *(const short4v*)(Wi + (size_t)g * EMBD + koff);
        #pragma unroll
        for (int r = 0; r < 2; ++r)
          acc[r][ct] = __builtin_amdgcn_mfma_f32_16x16x16bf16_1k(a[r], b, acc[r][ct], 0, 0, 0);
      }
    }
    if (t > 0) {                                   // h @ W_hh^T, K=128 in 8 chunks
      #pragma unroll
      for (int kc = 0; kc < 8; ++kc) {
        const int koff = kc * 16 + quad * 4;
        short4v a[2];
        #pragma unroll
        for (int r = 0; r < 2; ++r)
          a[r] = *(const short4v*)(h_bf + (size_t)(n0 + r * 16 + mrow) * HD + koff);
        #pragma unroll
        for (int ct = 0; ct < 8; ++ct) {
          const int g = colbase + ct * 16 + mrow;
          short4v b = *(const short4v*)(Wh + (size_t)g * HD + koff);
          #pragma unroll
          for (int r = 0; r < 2; ++r)
            acc[r][ct] = __builtin_amdgcn_mfma_f32_16x16x16bf16_1k(a[r], b, acc[r][ct], 0, 0, 0);
        }
      }
    }
    int lm[4], ln[4];
    #pragma unroll
    for (int reg = 0; reg < 4; ++reg) {
      const int v = lut16[lane * 4 + reg];
      lm[reg] = v >> 4; ln[reg] = v & 15;
    }
    #pragma unroll
    for (int r = 0; r < 2; ++r)
      #pragma unroll
      for (int ct = 0; ct < 8; ++ct)
        #pragma unroll
        for (int reg = 0; reg < 4; ++reg)
          gates[(r * 16 + lm[reg]) * G4 + colbase + ct * 16 + ln[reg]] = acc[r][ct][reg];
  }
#endif
  __syncthreads();

  // ---- cell update (gate order i,f,g,o) ----
  #pragma unroll
  for (int it = 0; it < 16; ++it) {
    const int lin = it * 256 + tid;
    const int nl = lin >> 7, j = lin & 127;
    const size_t n = (size_t)(n0 + nl);
    const float gi = gates[nl * G4 + j]       + ldf(b_ih, j, isbf)       + ldf(b_hh, j, isbf);
    const float gf = gates[nl * G4 + 128 + j] + ldf(b_ih, 128 + j, isbf) + ldf(b_hh, 128 + j, isbf);
    const float gg = gates[nl * G4 + 256 + j] + ldf(b_ih, 256 + j, isbf) + ldf(b_hh, 256 + j, isbf);
    const float go = gates[nl * G4 + 384 + j] + ldf(b_ih, 384 + j, isbf) + ldf(b_hh, 384 + j, isbf);
    const float iv = sigf(gi), fv = sigf(gf), gv = tanhf(gg), ov = sigf(go);
    const float cold = (t == 0) ? 0.f : cstate[n * HD + j];
    const float cnew = fv * cold + iv * gv;
    cstate[n * HD + j] = cnew;
    h_bf[n * HD + j] = (bf16)(ov * tanhf(cnew));
  }
}

// ================= LSTM step: VALU path (runs only if MFMA unverified) ==========
// 256 threads / 32 nodes. Thread owns col jj for 16 nodes, all 4 gates in regs.
// Weights staged from transposed WT via LDS chunks; no 64KB gates buffer.
__global__ __launch_bounds__(256, 4) void k_lstm_valu(
    const void* __restrict__ x_user, const bf16* __restrict__ WT,
    const void* __restrict__ b_ih, const void* __restrict__ b_hh,
    bf16* __restrict__ h_bf, float* __restrict__ cstate,
    const int* __restrict__ flagp, const int* __restrict__ ok32p,
    const int* __restrict__ ok16p, int t)
{
  const int isbf = *flagp;
  if (isbf && (*ok32p || *ok16p)) return;
  __shared__ float xh[32 * KTOT];      // 24 KB
  __shared__ bf16 wbuf[16 * G4];       // 16 KB
  const int tid = threadIdx.x;
  const int n0 = blockIdx.x * 32;

  // stage x_t (k 0..63) and h_{t-1} (k 64..191)
  #pragma unroll
  for (int i = 0; i < 8; ++i) {
    const int idx = tid + i * 256;
    const int n = idx >> 6, k = idx & 63;
    xh[n * KTOT + k] = ldf(x_user, (size_t)(n0 + n) * (T_STEPS * EMBD) + (size_t)t * EMBD + k, isbf);
  }
  #pragma unroll
  for (int i = 0; i < 16; ++i) {
    const int idx = tid + i * 256;
    const int n = idx >> 7, k = idx & 127;
    xh[n * KTOT + EMBD + k] = (t == 0) ? 0.f : (float)h_bf[(size_t)(n0 + n) * HD + k];
  }

  const int jj = tid & 127, grp = tid >> 7;
  const float bi = ldf(b_ih, jj, isbf)        + ldf(b_hh, jj, isbf);
  const float bfv = ldf(b_ih, 128 + jj, isbf) + ldf(b_hh, 128 + jj, isbf);
  const float bg = ldf(b_ih, 256 + jj, isbf)  + ldf(b_hh, 256 + jj, isbf);
  const float bo = ldf(b_ih, 384 + jj, isbf)  + ldf(b_hh, 384 + jj, isbf);
  float aI[16], aF[16], aG[16], aO[16];
  #pragma unroll
  for (int n = 0; n < 16; ++n) { aI[n] = 0.f; aF[n] = 0.f; aG[n] = 0.f; aO[n] = 0.f; }
  const float* xrow = xh + grp * 16 * KTOT;

  for (int c = 0; c < 12; ++c) {
    __syncthreads();                               // xh ready (c=0) / wbuf readers done
    const uint4* srcw = (const uint4*)(WT + c * 16 * G4);
    uint4* dstw = (uint4*)wbuf;
    #pragma unroll
    for (int i = 0; i < 4; ++i) dstw[tid + i * 256] = srcw[tid + i * 256];
    __syncthreads();
    for (int kk = 0; kk < 16; ++kk) {
      const int k = c * 16 + kk;
      const float wI = (float)wbuf[kk * G4 + jj];
      const float wF = (float)wbuf[kk * G4 + 128 + jj];
      const float wG = (float)wbuf[kk * G4 + 256 + jj];
      const float wO = (float)wbuf[kk * G4 + 384 + jj];
      #pragma unroll
      for (int n = 0; n < 16; ++n) {
        const float a = xrow[n * KTOT + k];
        aI[n] += a * wI; aF[n] += a * wF; aG[n] += a * wG; aO[n] += a * wO;
      }
    }
  }

  // cell update in registers (gate order i,f,g,o)
  #pragma unroll
  for (int n = 0; n < 16; ++n) {
    const size_t node = (size_t)(n0 + grp * 16 + n);
    const float iv = sigf(aI[n] + bi);
    const float fv = sigf(aF[n] + bfv);
    const float gv = tanhf(aG[n] + bg);
    const float ov = sigf(aO[n] + bo);
    const float cold = (t == 0) ? 0.f : cstate[node * HD + jj];
    const float cnew = fv * cold + iv * gv;
    cstate[node * HD + jj] = cnew;
    h_bf[node * HD + jj] = (bf16)(ov * tanhf(cnew));
  }
}

// ---------------- content linear ----------------
__global__ __launch_bounds__(256) void k_content(
    const void* __restrict__ x_content, const void* __restrict__ Wc,
    const void* __restrict__ bc, bf16* __restrict__ c_out,
    const int* __restrict__ flagp)
{
  __shared__ float xl[32 * EMBD];
  const int isbf = *flagp;
  const int tid = threadIdx.x;
  const int n0 = blockIdx.x * 32;
  #pragma unroll
  for (int i = 0; i < 8; ++i) {
    const int idx = tid + i * 256;
    xl[idx] = ldf(x_content, (size_t)n0 * EMBD + idx, isbf);
  }
  __syncthreads();
  const int jj = tid & 127, grp = tid >> 7;
  float acc[16];
  #pragma unroll
  for (int nn = 0; nn < 16; ++nn) acc[nn] = 0.f;
  for (int k = 0; k < EMBD; ++k) {
    const float w = ldf(Wc, (size_t)jj * EMBD + k, isbf);
    #pragma unroll
    for (int nn = 0; nn < 16; ++nn)
      acc[nn] += xl[(grp * 16 + nn) * EMBD + k] * w;
  }
  const float bj = ldf(bc, jj, isbf);
  #pragma unroll
  for (int nn = 0; nn < 16; ++nn)
    c_out[(size_t)(n0 + grp * 16 + nn) * HD + jj] = (bf16)(acc[nn] + bj);
}

// ================= CSR build =================
__global__ void k_count_int(const int* __restrict__ src, const int* __restrict__ dst,
                            int* __restrict__ deg_u, int* __restrict__ deg_c, int E)
{
  const int e = blockIdx.x * blockDim.x + threadIdx.x;
  if (e < E) {
    atomicAdd(deg_u + (src[e] & NMASK), 1);
    atomicAdd(deg_c + (dst[e] & NMASK), 1);
  }
}

__global__ __launch_bounds__(256) void k_scan(const int* __restrict__ deg,
                                              int* __restrict__ row, int* __restrict__ cur)
{
  __shared__ int part[256];
  const int tid = threadIdx.x;
  const int base = tid * 128;
  int s = 0;
  for (int i = 0; i < 128; ++i) s += deg[base + i];
  part[tid] = s;
  __syncthreads();
  if (tid == 0) {
    int a = 0;
    for (int i = 0; i < 256; ++i) { const int v = part[i]; part[i] = a; a += v; }
  }
  __syncthreads();
  int a = part[tid];
  for (int i = 0; i < 128; ++i) {
    row[base + i] = a; cur[base + i] = a;
    a += deg[base + i];
  }
  if (tid == 255) row[N_NODES] = a;
}

__global__ void k_build(const int* __restrict__ src, const int* __restrict__ dst,
                        int* __restrict__ cur_u, int* __restrict__ cur_c,
                        int* __restrict__ adj_u, int* __restrict__ adj_c, int E)
{
  const int e = blockIdx.x * blockDim.x + threadIdx.x;
  if (e < E) {
    const int s = src[e] & NMASK, d = dst[e] & NMASK;
    const int pc = atomicAdd(cur_c + d, 1);
    adj_c[pc] = s;
    const int pu = atomicAdd(cur_u + s, 1);
    adj_u[pu] = d;
  }
}

// gather-sum: agg[n][:] = sum over adj rows of feat. One wave per node.
__global__ __launch_bounds__(256) void k_gather(
    const bf16* __restrict__ feat, const int* __restrict__ adj,
    const int* __restrict__ row, float* __restrict__ agg)
{
  const int node = blockIdx.x * 4 + (threadIdx.x >> 6);
  const int lane = threadIdx.x & 63;
  const int beg = row[node], end = row[node + 1];
  float a0 = 0.f, a1 = 0.f;
  for (int p = beg; p < end; ++p) {
    const int s = adj[p];
    const bf16x2 v = *(const bf16x2*)(feat + (size_t)s * HD + 2 * lane);
    a0 += (float)v.x; a1 += (float)v.y;
  }
  float2* o = (float2*)(agg + (size_t)node * HD + 2 * lane);
  *o = float2{a0, a1};
}

// ---------------- SAGE linear ----------------
__global__ __launch_bounds__(256) void k_sage_lin(
    const float* __restrict__ agg, const int* __restrict__ cnt,
    const bf16* __restrict__ dstx,
    const void* __restrict__ Wl, const void* __restrict__ bl,
    const void* __restrict__ Wr, bf16* __restrict__ outp,
    const int* __restrict__ flagp)
{
  __shared__ float ml[32 * HD];
  __shared__ float xl[32 * HD];
  const int isbf = *flagp;
  const int tid = threadIdx.x;
  const int n0 = blockIdx.x * 32;
  #pragma unroll
  for (int i = 0; i < 16; ++i) {
    const int idx = tid + i * 256;
    const int n = idx >> 7;
    const float rc = 1.f / fmaxf((float)cnt[n0 + n], 1.f);
    ml[idx] = agg[(size_t)n0 * HD + idx] * rc;
    xl[idx] = (float)dstx[(size_t)n0 * HD + idx];
  }
  __syncthreads();
  const int jj = tid & 127, grp = tid >> 7;
  float acc[16];
  #pragma unroll
  for (int nn = 0; nn < 16; ++nn) acc[nn] = 0.f;
  for (int k = 0; k < HD; ++k) {
    const float wl = ldf(Wl, (size_t)jj * HD + k, isbf);
    const float wr = ldf(Wr, (size_t)jj * HD + k, isbf);
    #pragma unroll
    for (int nn = 0; nn < 16; ++nn)
      acc[nn] += ml[(grp * 16 + nn) * HD + k] * wl + xl[(grp * 16 + nn) * HD + k] * wr;
  }
  const float bj = ldf(bl, jj, isbf);
  #pragma unroll
  for (int nn = 0; nn < 16; ++nn)
    outp[(size_t)(n0 + grp * 16 + nn) * HD + jj] = (bf16)fmaxf(acc[nn] + bj, 0.f);
}

// ---------------- classifier hidden ----------------
__global__ __launch_bounds__(256) void k_cls(
    const bf16* __restrict__ u, const bf16* __restrict__ c,
    const void* __restrict__ W1, const void* __restrict__ b1,
    float* __restrict__ h1, const int* __restrict__ flagp)
{
  __shared__ float ul[32 * HD];
  __shared__ float cl[32 * HD];
  const int isbf = *flagp;
  const int tid = threadIdx.x;
  const int n0 = blockIdx.x * 32;
  #pragma unroll
  for (int i = 0; i < 16; ++i) {
    const int idx = tid + i * 256;
    ul[idx] = (float)u[(size_t)n0 * HD + idx];
    cl[idx] = (float)c[(size_t)n0 * HD + idx];
  }
  __syncthreads();
  const int jj = tid & 127, grp = tid >> 7;
  float acc[16];
  #pragma unroll
  for (int nn = 0; nn < 16; ++nn) acc[nn] = 0.f;
  for (int k = 0; k < HD; ++k) {
    const float wu = ldf(W1, (size_t)jj * 256 + k, isbf);
    const float wc = ldf(W1, (size_t)jj * 256 + 128 + k, isbf);
    #pragma unroll
    for (int nn = 0; nn < 16; ++nn)
      acc[nn] += ul[(grp * 16 + nn) * HD + k] * wu + cl[(grp * 16 + nn) * HD + k] * wc;
  }
  const float bj = ldf(b1, jj, isbf);
  #pragma unroll
  for (int nn = 0; nn < 16; ++nn)
    h1[(size_t)(n0 + grp * 16 + nn) * HD + jj] = fmaxf(acc[nn] + bj, 0.f);
}

// ---------------- output ----------------
__global__ __launch_bounds__(256) void k_out(
    const float* __restrict__ h1, const void* __restrict__ W2,
    const void* __restrict__ b2, void* __restrict__ out,
    const int* __restrict__ flagp)
{
  const int isbf = *flagp;
  const int wave = threadIdx.x >> 6, lane = threadIdx.x & 63;
  const int n = blockIdx.x * 4 + wave;
  float v = h1[(size_t)n * HD + lane] * ldf(W2, lane, isbf)
          + h1[(size_t)n * HD + 64 + lane] * ldf(W2, 64 + lane, isbf);
  #pragma unroll
  for (int off = 32; off > 0; off >>= 1) v += __shfl_down(v, off, 64);
  if (lane == 0) {
    const float r = sigf(v + ldf(b2, 0, isbf));
    if (isbf) ((bf16*)out)[n] = (bf16)r; else ((float*)out)[n] = r;
  }
}

// ---------------- diagnostic timing side-channel ----------------
// spins 150us*isbf + 300us*ok32 + 600us*ok16 (s_memrealtime ~100 MHz)
__global__ void k_diag(const int* __restrict__ flagp, const int* __restrict__ ok32p,
                       const int* __restrict__ ok16p)
{
  if (threadIdx.x != 0 || blockIdx.x != 0) return;
  const long long units = (*flagp ? 1 : 0) + (*ok32p ? 2 : 0) + (*ok16p ? 4 : 0);
  const long long target = units * 15000;   // 150 us per unit at 100 MHz
  const long long t0 = (long long)__builtin_amdgcn_s_memrealtime();
  long long i = 0;
  while (((long long)__builtin_amdgcn_s_memrealtime() - t0) < target && i < (1LL << 27)) ++i;
}

extern "C" void kernel_launch(void* const* d_in, const int* in_sizes, int n_in,
                              void* d_out, int out_size, void* d_ws, size_t ws_size,
                              hipStream_t stream)
{
  const void* x_user    = d_in[0];
  const void* x_content = d_in[1];
  const int*  edge      = (const int*)d_in[2];
  const void* W_ih      = d_in[3];
  const void* W_hh      = d_in[4];
  const void* b_ih      = d_in[5];
  const void* b_hh      = d_in[6];
  const void* Wc        = d_in[7];
  const void* bc        = d_in[8];
  const void* Wl[2]     = {d_in[9],  d_in[12]};
  const void* blv[2]    = {d_in[10], d_in[13]};
  const void* Wr[2]     = {d_in[11], d_in[14]};
  const void* W1        = d_in[15];
  const void* b1        = d_in[16];
  const void* W2        = d_in[17];
  const void* b2        = d_in[18];

  const int E = in_sizes[2] / 2;
  const int* src = edge;
  const int* dst = edge + E;

  // ---- workspace layout (< 59 MB; ~80 MB proven available) ----
  const size_t MB = 1u << 20;
  char* ws = (char*)d_ws;
  float* agg  = (float*)ws;                  // 16 MB fp32: cstate -> agg -> h1
  float* cst  = agg;
  float* h1   = agg;
  bf16* u0 = (bf16*)(ws + 16 * MB);          // 8 MB: LSTM h / u ping
  bf16* c0 = (bf16*)(ws + 24 * MB);          // 8 MB
  bf16* u1 = (bf16*)(ws + 32 * MB);          // 8 MB
  bf16* c1 = (bf16*)(ws + 40 * MB);          // 8 MB
  int*  adj_c = (int*)(ws + 48 * MB);        // 4 MB
  int*  adj_u = (int*)(ws + 52 * MB);        // 4 MB
  int*  meta  = (int*)(ws + 56 * MB);
  int* deg_u = meta;                         // 32768
  int* deg_c = deg_u + N_NODES;              // 32768
  int* row_u = deg_c + N_NODES;              // 32769
  int* row_c = row_u + N_NODES + 1;          // 32769
  int* cur_u = row_c + N_NODES + 1;          // 32768
  int* cur_c = cur_u + N_NODES;              // 32768
  int* flag  = cur_c + N_NODES;
  int* ok32  = flag + 1;
  int* ok16  = flag + 2;
  int* lut32 = flag + 4;                     // 256
  int* lut16 = lut32 + 256;                  // 256
  bf16* WT   = (bf16*)(ws + 58 * MB);        // 192*512*2 = 384 KB
  unsigned short* fr = (unsigned short*)(ws + 58 * MB + 512 * 1024);  // 16 KB probe scratch

  // ---- probes + weight transpose ----
  k_detect<<<1, 64, 0, stream>>>((const unsigned*)x_user, flag);
  k_probe<<<1, 64, 0, stream>>>(fr, lut32, ok32, lut16, ok16);
  k_wt<<<(KTOT * G4 + 255) / 256, 256, 0, stream>>>(W_ih, W_hh, WT, flag);

  // ---- LSTM 20 steps (both kernels flag-gated; exactly one does work) ----
  for (int t = 0; t < T_STEPS; ++t) {
    k_lstm_mfma<<<N_NODES / 32, 256, 0, stream>>>(x_user, W_ih, W_hh, b_ih, b_hh,
                                                  u0, cst, flag, ok32, ok16,
                                                  lut32, lut16, t);
    k_lstm_valu<<<N_NODES / 32, 256, 0, stream>>>(x_user, WT, b_ih, b_hh,
                                                  u0, cst, flag, ok32, ok16, t);
  }
  // ---- content embedding ----
  k_content<<<N_NODES / 32, 256, 0, stream>>>(x_content, Wc, bc, c0, flag);

  // ---- CSR build ----
  k_zero_int<<<(2 * N_NODES + 255) / 256, 256, 0, stream>>>(deg_u, 2 * N_NODES);
  k_count_int<<<(E + 255) / 256, 256, 0, stream>>>(src, dst, deg_u, deg_c, E);
  k_scan<<<1, 256, 0, stream>>>(deg_u, row_u, cur_u);
  k_scan<<<1, 256, 0, stream>>>(deg_c, row_c, cur_c);
  k_build<<<(E + 255) / 256, 256, 0, stream>>>(src, dst, cur_u, cur_c, adj_u, adj_c, E);

  // ---- 2 SAGE layers ----
  bf16* ui = u0; bf16* ci = c0; bf16* uo = u1; bf16* co = c1;
  for (int L = 0; L < 2; ++L) {
    k_gather<<<N_NODES / 4, 256, 0, stream>>>(ui, adj_c, row_c, agg);   // users -> content
    k_sage_lin<<<N_NODES / 32, 256, 0, stream>>>(agg, deg_c, ci, Wl[L], blv[L], Wr[L], co, flag);
    k_gather<<<N_NODES / 4, 256, 0, stream>>>(ci, adj_u, row_u, agg);   // content -> users
    k_sage_lin<<<N_NODES / 32, 256, 0, stream>>>(agg, deg_u, ui, Wl[L], blv[L], Wr[L], uo, flag);
    bf16* t1 = ui; ui = uo; uo = t1;
    bf16* t2 = ci; ci = co; co = t2;
  }

  // ---- classifier ----
  k_cls<<<N_NODES / 32, 256, 0, stream>>>(ui, ci, W1, b1, h1, flag);
  k_out<<<N_NODES / 4, 256, 0, stream>>>(h1, W2, b2, d_out, flag);

  // ---- diagnostics (timing side-channel, read from rocprof table) ----
  k_diag<<<1, 64, 0, stream>>>(flag, ok32, ok16);
}

// Round 8
// 2866.969 us; speedup vs baseline: 5.9967x; 5.9967x over previous
//
#include <hip/hip_runtime.h>
#include <hip/hip_bf16.h>

// GNNRecommender: LSTM(20) + content linear + 2x bipartite SAGE (CSR gather) + classifier.
// Round 8: MEASURED facts from round-7 diag: inputs fp32 (isbf=0), MFMA 16x16x32_bf16
// verified working (ok32=1, LUT recovered on-device). MFMA LSTM now dtype-independent:
// x staged fp32->bf16 via LDS, weights pre-converted to bf16 (L2-resident), h kept bf16.
// Fallback = round-6 proven VALU (401us/step), gated on !ok32 (never runs).

typedef __bf16 bf16;
typedef __bf16 bf16x2 __attribute__((ext_vector_type(2)));
typedef __bf16 bf16x8 __attribute__((ext_vector_type(8)));
typedef float floatx4 __attribute__((ext_vector_type(4)));

#define N_NODES 32768
#define NMASK 32767
#define T_STEPS 20
#define EMBD 64
#define HD 128
#define G4 512   // 4*H gate width
#define XPAD 72  // xtile row stride (bf16 elems): breaks 16-way LDS bank conflict

__device__ __forceinline__ float sigf(float x) { return 1.f / (1.f + __expf(-x)); }

__device__ __forceinline__ float ldf(const void* p, size_t i, int isbf) {
  return isbf ? (float)((const bf16*)p)[i] : ((const float*)p)[i];
}

// exact-integer probe matrices (small ints => exact in bf16 and fp32)
__device__ __forceinline__ float A3f(int m, int k) { return (float)((m * 37 + k * 11) % 13 - 6); }
__device__ __forceinline__ float B3f(int k, int n) { return (float)((k * 7 + n * 29) % 11 - 5); }
__device__ __forceinline__ unsigned short bfb(float f) {
  return (unsigned short)(__float_as_uint(f) >> 16);
}

// ---------------- dtype probe: flag=1 bf16, 0 fp32 ----------------
__global__ void k_detect(const unsigned* __restrict__ x, int* __restrict__ flag)
{
  if (threadIdx.x == 0 && blockIdx.x == 0) {
    int cnt = 0;
    for (int i = 0; i < 256; ++i) {
      const unsigned w = x[i];
      const unsigned e0 = (w >> 7) & 0xffu;
      const unsigned e1 = (w >> 23) & 0xffu;
      const bool ok0 = (e0 >= 90u && e0 <= 141u) || ((w & 0x7fffu) == 0u);
      const bool ok1 = (e1 >= 90u && e1 <= 141u) || (((w >> 16) & 0x7fffu) == 0u);
      if (ok0 && ok1) ++cnt;
    }
    *flag = (cnt >= 200) ? 1 : 0;
  }
}

__global__ __launch_bounds__(256) void k_zero_int(int* __restrict__ p, int n)
{
  const int i = blockIdx.x * 256 + threadIdx.x;
  if (i < n) p[i] = 0;
}

// ================= MFMA probe (verified working in round 7) =================
// uint16 bit-pattern fragments through memory; label-LUT decode + bijectivity +
// exact-integer product check. ok32=1 measured on this HW.
__global__ __launch_bounds__(64) void k_probe(
    unsigned short* __restrict__ fr, int* __restrict__ lut32, int* __restrict__ ok32p)
{
  __shared__ int seen[256];
  __shared__ int fail;
  const int lane = threadIdx.x;
  const int mrow = lane & 15, quad = lane >> 4;
  const floatx4 vz = {0.f, 0.f, 0.f, 0.f};

  unsigned short* fa1 = fr + 0 * 512;
  unsigned short* fb1 = fr + 1 * 512;
  unsigned short* fa2 = fr + 2 * 512;
  unsigned short* fb2 = fr + 3 * 512;
  unsigned short* fa3 = fr + 4 * 512;
  unsigned short* fb3 = fr + 5 * 512;
  for (int j = 0; j < 8; ++j) {
    fa1[lane * 8 + j] = bfb((float)(mrow + 1));
    fb1[lane * 8 + j] = bfb(1.0f);
    fa2[lane * 8 + j] = bfb(1.0f);
    fb2[lane * 8 + j] = bfb((float)(mrow + 1));
    fa3[lane * 8 + j] = bfb(A3f(mrow, quad * 8 + j));
    fb3[lane * 8 + j] = bfb(B3f(quad * 8 + j, mrow));
  }
  for (int i = lane; i < 256; i += 64) seen[i] = 0;
  if (lane == 0) fail = 0;
  __syncthreads();
  {
    bf16x8 a1 = *(const bf16x8*)(fa1 + lane * 8);
    bf16x8 b1 = *(const bf16x8*)(fb1 + lane * 8);
    bf16x8 a2 = *(const bf16x8*)(fa2 + lane * 8);
    bf16x8 b2 = *(const bf16x8*)(fb2 + lane * 8);
    bf16x8 a3 = *(const bf16x8*)(fa3 + lane * 8);
    bf16x8 b3 = *(const bf16x8*)(fb3 + lane * 8);
    floatx4 r1 = __builtin_amdgcn_mfma_f32_16x16x32_bf16(a1, b1, vz, 0, 0, 0);
    floatx4 r2 = __builtin_amdgcn_mfma_f32_16x16x32_bf16(a2, b2, vz, 0, 0, 0);
    floatx4 r3 = __builtin_amdgcn_mfma_f32_16x16x32_bf16(a3, b3, vz, 0, 0, 0);
    #pragma unroll
    for (int reg = 0; reg < 4; ++reg) {
      const int m = __float2int_rn(r1[reg] * (1.f / 32.f)) - 1;
      const int n = __float2int_rn(r2[reg] * (1.f / 32.f)) - 1;
      bool good = (m >= 0 && m < 16 && n >= 0 && n < 16)
               && fabsf(r1[reg] - 32.f * (m + 1)) < 0.5f
               && fabsf(r2[reg] - 32.f * (n + 1)) < 0.5f;
      if (good) {
        float c3 = 0.f;
        for (int k = 0; k < 32; ++k) c3 += A3f(m, k) * B3f(k, n);
        good = fabsf(r3[reg] - c3) < 0.5f;
      }
      if (good) {
        atomicAdd(&seen[m * 16 + n], 1);
        lut32[lane * 4 + reg] = (m << 4) | n;
      } else fail = 1;
    }
  }
  __syncthreads();
  {
    int bij = 1;
    for (int i = lane; i < 256; i += 64) if (seen[i] != 1) bij = 0;
    if (!bij) fail = 1;
  }
  __syncthreads();
  if (lane == 0) *ok32p = fail ? 0 : 1;
}

// ---------------- weight conversion: row-major bf16 copies of W_ih, W_hh ----------
__global__ __launch_bounds__(256) void k_wconv(const void* __restrict__ W_ih,
                                               const void* __restrict__ W_hh,
                                               bf16* __restrict__ Wi_bf,
                                               bf16* __restrict__ Wh_bf,
                                               const int* __restrict__ flagp)
{
  const int isbf = *flagp;
  const int e = blockIdx.x * 256 + threadIdx.x;
  if (e < G4 * EMBD) Wi_bf[e] = (bf16)ldf(W_ih, e, isbf);
  if (e < G4 * HD)   Wh_bf[e] = (bf16)ldf(W_hh, e, isbf);
}

// ================= LSTM step: MFMA path (dtype-independent) =================
// 32 nodes/block, 256 threads, wave w owns gate cols [w*128,(w+1)*128).
// x_t tile staged fp32->bf16 in LDS (stride XPAD); gates scattered via measured LUT.
__global__ __launch_bounds__(256) void k_lstm_mfma(
    const void* __restrict__ x_user, const bf16* __restrict__ Wi_bf,
    const bf16* __restrict__ Wh_bf, const void* __restrict__ b_ih,
    const void* __restrict__ b_hh,
    bf16* __restrict__ h_bf, float* __restrict__ cstate,
    const int* __restrict__ flagp, const int* __restrict__ ok32p,
    const int* __restrict__ lut32, int t)
{
  if (!*ok32p) return;
  __shared__ float smem[32 * G4];           // 64 KB; first 4.5KB aliased as xtile
  bf16* xtile = (bf16*)smem;                // [32][XPAD]
  float* gates = smem;
  const int isbf = *flagp;
  const int tid = threadIdx.x;
  const int n0 = blockIdx.x * 32;

  // ---- stage x_t (any dtype) as bf16 into LDS ----
  #pragma unroll
  for (int i = 0; i < 8; ++i) {
    const int idx = tid + i * 256;          // 0..2047
    const int n = idx >> 6, k = idx & 63;
    xtile[n * XPAD + k] =
        (bf16)ldf(x_user, (size_t)(n0 + n) * (T_STEPS * EMBD) + (size_t)t * EMBD + k, isbf);
  }
  __syncthreads();

  const int wave = tid >> 6, lane = tid & 63;
  const int mrow = lane & 15, quad = lane >> 4;
  const int colbase = wave * 128;
  const floatx4 vz = {0.f, 0.f, 0.f, 0.f};
  floatx4 acc[2][8];
  #pragma unroll
  for (int r = 0; r < 2; ++r)
    #pragma unroll
    for (int c = 0; c < 8; ++c) acc[r][c] = vz;

  // ---- x_t @ W_ih^T (K=64) ----
  #pragma unroll
  for (int kc = 0; kc < 2; ++kc) {
    const int koff = kc * 32 + quad * 8;
    bf16x8 a[2];
    #pragma unroll
    for (int r = 0; r < 2; ++r)
      a[r] = *(const bf16x8*)(xtile + (r * 16 + mrow) * XPAD + koff);
    #pragma unroll
    for (int ct = 0; ct < 8; ++ct) {
      const int g = colbase + ct * 16 + mrow;
      bf16x8 b = *(const bf16x8*)(Wi_bf + (size_t)g * EMBD + koff);
      #pragma unroll
      for (int r = 0; r < 2; ++r)
        acc[r][ct] = __builtin_amdgcn_mfma_f32_16x16x32_bf16(a[r], b, acc[r][ct], 0, 0, 0);
    }
  }
  // ---- h_{t-1} @ W_hh^T (K=128) ----
  if (t > 0) {
    #pragma unroll
    for (int kc = 0; kc < 4; ++kc) {
      const int koff = kc * 32 + quad * 8;
      bf16x8 a[2];
      #pragma unroll
      for (int r = 0; r < 2; ++r)
        a[r] = *(const bf16x8*)(h_bf + (size_t)(n0 + r * 16 + mrow) * HD + koff);
      #pragma unroll
      for (int ct = 0; ct < 8; ++ct) {
        const int g = colbase + ct * 16 + mrow;
        bf16x8 b = *(const bf16x8*)(Wh_bf + (size_t)g * HD + koff);
        #pragma unroll
        for (int r = 0; r < 2; ++r)
          acc[r][ct] = __builtin_amdgcn_mfma_f32_16x16x32_bf16(a[r], b, acc[r][ct], 0, 0, 0);
      }
    }
  }
  __syncthreads();                          // all xtile reads done before gates overwrite

  // ---- scatter gates via measured (lane,reg)->(m,n) LUT ----
  int lm[4], ln[4];
  #pragma unroll
  for (int reg = 0; reg < 4; ++reg) {
    const int v = lut32[lane * 4 + reg];
    lm[reg] = v >> 4; ln[reg] = v & 15;
  }
  #pragma unroll
  for (int r = 0; r < 2; ++r)
    #pragma unroll
    for (int ct = 0; ct < 8; ++ct)
      #pragma unroll
      for (int reg = 0; reg < 4; ++reg)
        gates[(r * 16 + lm[reg]) * G4 + colbase + ct * 16 + ln[reg]] = acc[r][ct][reg];
  __syncthreads();

  // ---- cell update (gate order i,f,g,o) ----
  #pragma unroll
  for (int it = 0; it < 16; ++it) {
    const int lin = it * 256 + tid;
    const int nl = lin >> 7, j = lin & 127;
    const size_t n = (size_t)(n0 + nl);
    const float gi = gates[nl * G4 + j]       + ldf(b_ih, j, isbf)       + ldf(b_hh, j, isbf);
    const float gf = gates[nl * G4 + 128 + j] + ldf(b_ih, 128 + j, isbf) + ldf(b_hh, 128 + j, isbf);
    const float gg = gates[nl * G4 + 256 + j] + ldf(b_ih, 256 + j, isbf) + ldf(b_hh, 256 + j, isbf);
    const float go = gates[nl * G4 + 384 + j] + ldf(b_ih, 384 + j, isbf) + ldf(b_hh, 384 + j, isbf);
    const float iv = sigf(gi), fv = sigf(gf), gv = tanhf(gg), ov = sigf(go);
    const float cold = (t == 0) ? 0.f : cstate[n * HD + j];
    const float cnew = fv * cold + iv * gv;
    cstate[n * HD + j] = cnew;
    h_bf[n * HD + j] = (bf16)(ov * tanhf(cnew));
  }
}

// ================= LSTM step: VALU fallback (round-6 proven, runs iff !ok32) ======
__global__ __launch_bounds__(256) void k_lstm_valu(
    const void* __restrict__ x_user, const void* __restrict__ W_ih,
    const void* __restrict__ W_hh, const void* __restrict__ b_ih,
    const void* __restrict__ b_hh,
    bf16* __restrict__ h_bf, float* __restrict__ cstate,
    const int* __restrict__ flagp, const int* __restrict__ ok32p, int t)
{
  if (*ok32p) return;
  __shared__ float smem[32 * G4];
  const int isbf = *flagp;
  const int tid = threadIdx.x;
  const int n0 = blockIdx.x * 32;
  float* gates = smem;
  float* xl = smem;                          // 32x64
  float* hl = smem + 32 * EMBD;              // 32x128
  #pragma unroll
  for (int i = 0; i < 8; ++i) {
    const int idx = tid + i * 256;
    const int n = idx >> 6, k = idx & 63;
    xl[idx] = ldf(x_user, (size_t)(n0 + n) * (T_STEPS * EMBD) + (size_t)t * EMBD + k, isbf);
  }
  #pragma unroll
  for (int i = 0; i < 16; ++i) {
    const int idx = tid + i * 256;
    hl[idx] = (t == 0) ? 0.f : (float)h_bf[(size_t)n0 * HD + idx];
  }
  __syncthreads();
  const int col0 = tid, col1 = tid + 256;
  float acc0[32], acc1[32];
  #pragma unroll
  for (int n = 0; n < 32; ++n) { acc0[n] = 0.f; acc1[n] = 0.f; }
  for (int k = 0; k < EMBD; ++k) {
    const float w0 = ldf(W_ih, (size_t)col0 * EMBD + k, isbf);
    const float w1 = ldf(W_ih, (size_t)col1 * EMBD + k, isbf);
    #pragma unroll
    for (int n = 0; n < 32; ++n) {
      const float a = xl[n * EMBD + k];
      acc0[n] += a * w0; acc1[n] += a * w1;
    }
  }
  if (t > 0) {
    for (int k = 0; k < HD; ++k) {
      const float w0 = ldf(W_hh, (size_t)col0 * HD + k, isbf);
      const float w1 = ldf(W_hh, (size_t)col1 * HD + k, isbf);
      #pragma unroll
      for (int n = 0; n < 32; ++n) {
        const float a = hl[n * HD + k];
        acc0[n] += a * w0; acc1[n] += a * w1;
      }
    }
  }
  __syncthreads();
  #pragma unroll
  for (int n = 0; n < 32; ++n) {
    gates[n * G4 + col0] = acc0[n];
    gates[n * G4 + col1] = acc1[n];
  }
  __syncthreads();
  #pragma unroll
  for (int it = 0; it < 16; ++it) {
    const int lin = it * 256 + tid;
    const int nl = lin >> 7, j = lin & 127;
    const size_t n = (size_t)(n0 + nl);
    const float gi = gates[nl * G4 + j]       + ldf(b_ih, j, isbf)       + ldf(b_hh, j, isbf);
    const float gf = gates[nl * G4 + 128 + j] + ldf(b_ih, 128 + j, isbf) + ldf(b_hh, 128 + j, isbf);
    const float gg = gates[nl * G4 + 256 + j] + ldf(b_ih, 256 + j, isbf) + ldf(b_hh, 256 + j, isbf);
    const float go = gates[nl * G4 + 384 + j] + ldf(b_ih, 384 + j, isbf) + ldf(b_hh, 384 + j, isbf);
    const float iv = sigf(gi), fv = sigf(gf), gv = tanhf(gg), ov = sigf(go);
    const float cold = (t == 0) ? 0.f : cstate[n * HD + j];
    const float cnew = fv * cold + iv * gv;
    cstate[n * HD + j] = cnew;
    h_bf[n * HD + j] = (bf16)(ov * tanhf(cnew));
  }
}

// ---------------- content linear ----------------
__global__ __launch_bounds__(256) void k_content(
    const void* __restrict__ x_content, const void* __restrict__ Wc,
    const void* __restrict__ bc, bf16* __restrict__ c_out,
    const int* __restrict__ flagp)
{
  __shared__ float xl[32 * EMBD];
  const int isbf = *flagp;
  const int tid = threadIdx.x;
  const int n0 = blockIdx.x * 32;
  #pragma unroll
  for (int i = 0; i < 8; ++i) {
    const int idx = tid + i * 256;
    xl[idx] = ldf(x_content, (size_t)n0 * EMBD + idx, isbf);
  }
  __syncthreads();
  const int jj = tid & 127, grp = tid >> 7;
  float acc[16];
  #pragma unroll
  for (int nn = 0; nn < 16; ++nn) acc[nn] = 0.f;
  for (int k = 0; k < EMBD; ++k) {
    const float w = ldf(Wc, (size_t)jj * EMBD + k, isbf);
    #pragma unroll
    for (int nn = 0; nn < 16; ++nn)
      acc[nn] += xl[(grp * 16 + nn) * EMBD + k] * w;
  }
  const float bj = ldf(bc, jj, isbf);
  #pragma unroll
  for (int nn = 0; nn < 16; ++nn)
    c_out[(size_t)(n0 + grp * 16 + nn) * HD + jj] = (bf16)(acc[nn] + bj);
}

// ================= CSR build =================
__global__ void k_count_int(const int* __restrict__ src, const int* __restrict__ dst,
                            int* __restrict__ deg_u, int* __restrict__ deg_c, int E)
{
  const int e = blockIdx.x * blockDim.x + threadIdx.x;
  if (e < E) {
    atomicAdd(deg_u + (src[e] & NMASK), 1);
    atomicAdd(deg_c + (dst[e] & NMASK), 1);
  }
}

__global__ __launch_bounds__(256) void k_scan(const int* __restrict__ deg,
                                              int* __restrict__ row, int* __restrict__ cur)
{
  __shared__ int part[256];
  const int tid = threadIdx.x;
  const int base = tid * 128;
  int s = 0;
  for (int i = 0; i < 128; ++i) s += deg[base + i];
  part[tid] = s;
  __syncthreads();
  if (tid == 0) {
    int a = 0;
    for (int i = 0; i < 256; ++i) { const int v = part[i]; part[i] = a; a += v; }
  }
  __syncthreads();
  int a = part[tid];
  for (int i = 0; i < 128; ++i) {
    row[base + i] = a; cur[base + i] = a;
    a += deg[base + i];
  }
  if (tid == 255) row[N_NODES] = a;
}

__global__ void k_build(const int* __restrict__ src, const int* __restrict__ dst,
                        int* __restrict__ cur_u, int* __restrict__ cur_c,
                        int* __restrict__ adj_u, int* __restrict__ adj_c, int E)
{
  const int e = blockIdx.x * blockDim.x + threadIdx.x;
  if (e < E) {
    const int s = src[e] & NMASK, d = dst[e] & NMASK;
    const int pc = atomicAdd(cur_c + d, 1);
    adj_c[pc] = s;
    const int pu = atomicAdd(cur_u + s, 1);
    adj_u[pu] = d;
  }
}

// gather-sum: agg[n][:] = sum over adj rows of feat. One wave per node.
__global__ __launch_bounds__(256) void k_gather(
    const bf16* __restrict__ feat, const int* __restrict__ adj,
    const int* __restrict__ row, float* __restrict__ agg)
{
  const int node = blockIdx.x * 4 + (threadIdx.x >> 6);
  const int lane = threadIdx.x & 63;
  const int beg = row[node], end = row[node + 1];
  float a0 = 0.f, a1 = 0.f;
  for (int p = beg; p < end; ++p) {
    const int s = adj[p];
    const bf16x2 v = *(const bf16x2*)(feat + (size_t)s * HD + 2 * lane);
    a0 += (float)v.x; a1 += (float)v.y;
  }
  float2* o = (float2*)(agg + (size_t)node * HD + 2 * lane);
  *o = float2{a0, a1};
}

// ---------------- SAGE linear ----------------
__global__ __launch_bounds__(256) void k_sage_lin(
    const float* __restrict__ agg, const int* __restrict__ cnt,
    const bf16* __restrict__ dstx,
    const void* __restrict__ Wl, const void* __restrict__ bl,
    const void* __restrict__ Wr, bf16* __restrict__ outp,
    const int* __restrict__ flagp)
{
  __shared__ float ml[32 * HD];
  __shared__ float xl[32 * HD];
  const int isbf = *flagp;
  const int tid = threadIdx.x;
  const int n0 = blockIdx.x * 32;
  #pragma unroll
  for (int i = 0; i < 16; ++i) {
    const int idx = tid + i * 256;
    const int n = idx >> 7;
    const float rc = 1.f / fmaxf((float)cnt[n0 + n], 1.f);
    ml[idx] = agg[(size_t)n0 * HD + idx] * rc;
    xl[idx] = (float)dstx[(size_t)n0 * HD + idx];
  }
  __syncthreads();
  const int jj = tid & 127, grp = tid >> 7;
  float acc[16];
  #pragma unroll
  for (int nn = 0; nn < 16; ++nn) acc[nn] = 0.f;
  for (int k = 0; k < HD; ++k) {
    const float wl = ldf(Wl, (size_t)jj * HD + k, isbf);
    const float wr = ldf(Wr, (size_t)jj * HD + k, isbf);
    #pragma unroll
    for (int nn = 0; nn < 16; ++nn)
      acc[nn] += ml[(grp * 16 + nn) * HD + k] * wl + xl[(grp * 16 + nn) * HD + k] * wr;
  }
  const float bj = ldf(bl, jj, isbf);
  #pragma unroll
  for (int nn = 0; nn < 16; ++nn)
    outp[(size_t)(n0 + grp * 16 + nn) * HD + jj] = (bf16)fmaxf(acc[nn] + bj, 0.f);
}

// ---------------- classifier hidden ----------------
__global__ __launch_bounds__(256) void k_cls(
    const bf16* __restrict__ u, const bf16* __restrict__ c,
    const void* __restrict__ W1, const void* __restrict__ b1,
    float* __restrict__ h1, const int* __restrict__ flagp)
{
  __shared__ float ul[32 * HD];
  __shared__ float cl[32 * HD];
  const int isbf = *flagp;
  const int tid = threadIdx.x;
  const int n0 = blockIdx.x * 32;
  #pragma unroll
  for (int i = 0; i < 16; ++i) {
    const int idx = tid + i * 256;
    ul[idx] = (float)u[(size_t)n0 * HD + idx];
    cl[idx] = (float)c[(size_t)n0 * HD + idx];
  }
  __syncthreads();
  const int jj = tid & 127, grp = tid >> 7;
  float acc[16];
  #pragma unroll
  for (int nn = 0; nn < 16; ++nn) acc[nn] = 0.f;
  for (int k = 0; k < HD; ++k) {
    const float wu = ldf(W1, (size_t)jj * 256 + k, isbf);
    const float wc = ldf(W1, (size_t)jj * 256 + 128 + k, isbf);
    #pragma unroll
    for (int nn = 0; nn < 16; ++nn)
      acc[nn] += ul[(grp * 16 + nn) * HD + k] * wu + cl[(grp * 16 + nn) * HD + k] * wc;
  }
  const float bj = ldf(b1, jj, isbf);
  #pragma unroll
  for (int nn = 0; nn < 16; ++nn)
    h1[(size_t)(n0 + grp * 16 + nn) * HD + jj] = fmaxf(acc[nn] + bj, 0.f);
}

// ---------------- output ----------------
__global__ __launch_bounds__(256) void k_out(
    const float* __restrict__ h1, const void* __restrict__ W2,
    const void* __restrict__ b2, void* __restrict__ out,
    const int* __restrict__ flagp)
{
  const int isbf = *flagp;
  const int wave = threadIdx.x >> 6, lane = threadIdx.x & 63;
  const int n = blockIdx.x * 4 + wave;
  float v = h1[(size_t)n * HD + lane] * ldf(W2, lane, isbf)
          + h1[(size_t)n * HD + 64 + lane] * ldf(W2, 64 + lane, isbf);
  #pragma unroll
  for (int off = 32; off > 0; off >>= 1) v += __shfl_down(v, off, 64);
  if (lane == 0) {
    const float r = sigf(v + ldf(b2, 0, isbf));
    if (isbf) ((bf16*)out)[n] = (bf16)r; else ((float*)out)[n] = r;
  }
}

// ---------------- diag side-channel: 10us * (isbf + 2*ok32) ----------------
__global__ void k_diag(const int* __restrict__ flagp, const int* __restrict__ ok32p)
{
  if (threadIdx.x != 0 || blockIdx.x != 0) return;
  const long long units = (*flagp ? 1 : 0) + (*ok32p ? 2 : 0);
  const long long target = units * 1000;    // 10 us per unit at 100 MHz
  const long long t0 = (long long)__builtin_amdgcn_s_memrealtime();
  long long i = 0;
  while (((long long)__builtin_amdgcn_s_memrealtime() - t0) < target && i < (1LL << 24)) ++i;
}

extern "C" void kernel_launch(void* const* d_in, const int* in_sizes, int n_in,
                              void* d_out, int out_size, void* d_ws, size_t ws_size,
                              hipStream_t stream)
{
  const void* x_user    = d_in[0];
  const void* x_content = d_in[1];
  const int*  edge      = (const int*)d_in[2];
  const void* W_ih      = d_in[3];
  const void* W_hh      = d_in[4];
  const void* b_ih      = d_in[5];
  const void* b_hh      = d_in[6];
  const void* Wc        = d_in[7];
  const void* bc        = d_in[8];
  const void* Wl[2]     = {d_in[9],  d_in[12]};
  const void* blv[2]    = {d_in[10], d_in[13]};
  const void* Wr[2]     = {d_in[11], d_in[14]};
  const void* W1        = d_in[15];
  const void* b1        = d_in[16];
  const void* W2        = d_in[17];
  const void* b2        = d_in[18];

  const int E = in_sizes[2] / 2;
  const int* src = edge;
  const int* dst = edge + E;

  // ---- workspace layout (< 59 MB; >=80 MB proven available) ----
  const size_t MB = 1u << 20;
  char* ws = (char*)d_ws;
  float* agg  = (float*)ws;                  // 16 MB fp32: cstate -> agg -> h1
  float* cst  = agg;
  float* h1   = agg;
  bf16* u0 = (bf16*)(ws + 16 * MB);          // 8 MB: LSTM h / u ping
  bf16* c0 = (bf16*)(ws + 24 * MB);          // 8 MB
  bf16* u1 = (bf16*)(ws + 32 * MB);          // 8 MB
  bf16* c1 = (bf16*)(ws + 40 * MB);          // 8 MB
  int*  adj_c = (int*)(ws + 48 * MB);        // 4 MB
  int*  adj_u = (int*)(ws + 52 * MB);        // 4 MB
  int*  meta  = (int*)(ws + 56 * MB);
  int* deg_u = meta;                         // 32768
  int* deg_c = deg_u + N_NODES;              // 32768
  int* row_u = deg_c + N_NODES;              // 32769
  int* row_c = row_u + N_NODES + 1;          // 32769
  int* cur_u = row_c + N_NODES + 1;          // 32768
  int* cur_c = cur_u + N_NODES;              // 32768
  int* flag  = cur_c + N_NODES;
  int* ok32  = flag + 1;
  int* lut32 = flag + 4;                     // 256
  bf16* Wi_bf = (bf16*)(ws + 58 * MB);       // 512*64*2  = 64 KB
  bf16* Wh_bf = Wi_bf + G4 * EMBD;           // 512*128*2 = 128 KB
  unsigned short* fr = (unsigned short*)(ws + 58 * MB + 256 * 1024);  // probe scratch

  // ---- probes + weight conversion ----
  k_detect<<<1, 64, 0, stream>>>((const unsigned*)x_user, flag);
  k_probe<<<1, 64, 0, stream>>>(fr, lut32, ok32);
  k_wconv<<<(G4 * HD + 255) / 256, 256, 0, stream>>>(W_ih, W_hh, Wi_bf, Wh_bf, flag);

  // ---- LSTM 20 steps (mfma iff ok32, valu iff !ok32) ----
  for (int t = 0; t < T_STEPS; ++t) {
    k_lstm_mfma<<<N_NODES / 32, 256, 0, stream>>>(x_user, Wi_bf, Wh_bf, b_ih, b_hh,
                                                  u0, cst, flag, ok32, lut32, t);
    k_lstm_valu<<<N_NODES / 32, 256, 0, stream>>>(x_user, W_ih, W_hh, b_ih, b_hh,
                                                  u0, cst, flag, ok32, t);
  }
  // ---- content embedding ----
  k_content<<<N_NODES / 32, 256, 0, stream>>>(x_content, Wc, bc, c0, flag);

  // ---- CSR build ----
  k_zero_int<<<(2 * N_NODES + 255) / 256, 256, 0, stream>>>(deg_u, 2 * N_NODES);
  k_count_int<<<(E + 255) / 256, 256, 0, stream>>>(src, dst, deg_u, deg_c, E);
  k_scan<<<1, 256, 0, stream>>>(deg_u, row_u, cur_u);
  k_scan<<<1, 256, 0, stream>>>(deg_c, row_c, cur_c);
  k_build<<<(E + 255) / 256, 256, 0, stream>>>(src, dst, cur_u, cur_c, adj_u, adj_c, E);

  // ---- 2 SAGE layers ----
  bf16* ui = u0; bf16* ci = c0; bf16* uo = u1; bf16* co = c1;
  for (int L = 0; L < 2; ++L) {
    k_gather<<<N_NODES / 4, 256, 0, stream>>>(ui, adj_c, row_c, agg);   // users -> content
    k_sage_lin<<<N_NODES / 32, 256, 0, stream>>>(agg, deg_c, ci, Wl[L], blv[L], Wr[L], co, flag);
    k_gather<<<N_NODES / 4, 256, 0, stream>>>(ci, adj_u, row_u, agg);   // content -> users
    k_sage_lin<<<N_NODES / 32, 256, 0, stream>>>(agg, deg_u, ui, Wl[L], blv[L], Wr[L], uo, flag);
    bf16* t1 = ui; ui = uo; uo = t1;
    bf16* t2 = ci; ci = co; co = t2;
  }

  // ---- classifier ----
  k_cls<<<N_NODES / 32, 256, 0, stream>>>(ui, ci, W1, b1, h1, flag);
  k_out<<<N_NODES / 4, 256, 0, stream>>>(h1, W2, b2, d_out, flag);

  // ---- diag (timing side-channel) ----
  k_diag<<<1, 64, 0, stream>>>(flag, ok32);
}